// Round 1
// baseline (713.734 us; speedup 1.0000x reference)
//
#include <hip/hip_runtime.h>
#include <math.h>

// Problem constants (from reference): B=2, S=4096, D=768, H=12, HD=64
#define B_  2
#define S_  4096
#define D_  768
#define H_  12
#define HD_ 64

using bf16x8  = __attribute__((ext_vector_type(8))) __bf16;
using f32x4   = __attribute__((ext_vector_type(4))) float;
using ushort8 = __attribute__((ext_vector_type(8))) unsigned short;

// fp32 -> bf16 bits, round-to-nearest-even (inputs are finite)
__device__ __forceinline__ unsigned short f2b(float f) {
    union { float f; unsigned u; } x; x.f = f;
    unsigned r = x.u + 0x7fffu + ((x.u >> 16) & 1u);
    return (unsigned short)(r >> 16);
}

// ---------------------------------------------------------------------------
// GEMM: C[M,N] = A[M,K] @ W[N,K]^T + bias[N]
// A is fp32 (A_IS_F32) or bf16-bits; W/bias fp32; C fp32 (OUT_F32) or bf16.
// 128x128 tile, BK=32, 4 waves of 64x64, mfma_f32_16x16x32_bf16.
// LDS pad +8 bf16 (row stride 80B) -> ds_read_b128 ~conflict-free.
// ---------------------------------------------------------------------------
template<bool A_IS_F32, bool OUT_F32>
__global__ __launch_bounds__(256)
void gemm_bias(const void* __restrict__ Ap, const float* __restrict__ W,
               const float* __restrict__ bias, void* __restrict__ Cp,
               int M, int N, int K)
{
    constexpr int BM = 128, BN = 128, BK = 32, LDP = BK + 8;
    __shared__ __align__(16) unsigned short As[BM * LDP];
    __shared__ __align__(16) unsigned short Bs[BN * LDP];

    const int tid  = threadIdx.x;
    const int bm   = blockIdx.x, bn = blockIdx.y;
    const int w    = tid >> 6, lane = tid & 63;
    const int lr   = lane & 15, lg = lane >> 4;
    const int wm   = (w >> 1) * 64, wn = (w & 1) * 64;

    f32x4 acc[4][4] = {};

    for (int k0 = 0; k0 < K; k0 += BK) {
        __syncthreads();
        // ---- stage A tile (convert fp32->bf16 if needed) ----
        if constexpr (A_IS_F32) {
            const float* A = (const float*)Ap;
            for (int t = 0; t < 4; ++t) {
                int idx = tid + t * 256;
                int row = idx >> 3, c4 = (idx & 7) * 4;
                const float4 v = *(const float4*)(A + (size_t)(bm * BM + row) * K + k0 + c4);
                unsigned short* dst = &As[row * LDP + c4];
                dst[0] = f2b(v.x); dst[1] = f2b(v.y); dst[2] = f2b(v.z); dst[3] = f2b(v.w);
            }
        } else {
            const unsigned short* A = (const unsigned short*)Ap;
            for (int t = 0; t < 2; ++t) {
                int idx = tid + t * 256;
                int row = idx >> 2, c8 = (idx & 3) * 8;
                *(ushort8*)&As[row * LDP + c8] =
                    *(const ushort8*)(A + (size_t)(bm * BM + row) * K + k0 + c8);
            }
        }
        // ---- stage W tile (always fp32, [N][K] row-major = B^T layout) ----
        for (int t = 0; t < 4; ++t) {
            int idx = tid + t * 256;
            int row = idx >> 3, c4 = (idx & 7) * 4;
            const float4 v = *(const float4*)(W + (size_t)(bn * BN + row) * K + k0 + c4);
            unsigned short* dst = &Bs[row * LDP + c4];
            dst[0] = f2b(v.x); dst[1] = f2b(v.y); dst[2] = f2b(v.z); dst[3] = f2b(v.w);
        }
        __syncthreads();

        // ---- fragments + 16 MFMAs ----
        bf16x8 af[4], bfr[4];
        for (int i = 0; i < 4; ++i)
            af[i] = *(const bf16x8*)&As[(wm + i * 16 + lr) * LDP + lg * 8];
        for (int j = 0; j < 4; ++j)
            bfr[j] = *(const bf16x8*)&Bs[(wn + j * 16 + lr) * LDP + lg * 8];
        for (int i = 0; i < 4; ++i)
            for (int j = 0; j < 4; ++j)
                acc[i][j] = __builtin_amdgcn_mfma_f32_16x16x32_bf16(af[i], bfr[j], acc[i][j], 0, 0, 0);
    }

    // ---- epilogue: C row = (lane>>4)*4+reg, col = lane&15 (verified layout) ----
    for (int i = 0; i < 4; ++i) {
        int row0 = bm * BM + wm + i * 16 + lg * 4;
        for (int j = 0; j < 4; ++j) {
            int col = bn * BN + wn + j * 16 + lr;
            float bv = bias[col];
            for (int r = 0; r < 4; ++r) {
                float val = acc[i][j][r] + bv;
                if constexpr (OUT_F32)
                    ((float*)Cp)[(size_t)(row0 + r) * N + col] = val;
                else
                    ((unsigned short*)Cp)[(size_t)(row0 + r) * N + col] = f2b(val);
            }
        }
    }
}

// ---------------------------------------------------------------------------
// Flash attention (causal). Block = (64 q-rows, one (b,h)); 4 waves x 16 rows.
// S-phase: S16x64 = Q16x64 @ K^T via mfma (A=Q, B=K row-major-in-LDS).
// Online softmax in fp32; P -> LDS (C-layout write, A-layout read); PV with
// V^T staged in LDS so B-operand reads are k-contiguous.
// ---------------------------------------------------------------------------
__global__ __launch_bounds__(256)
void attn_kernel(const unsigned short* __restrict__ Qp,
                 const unsigned short* __restrict__ Kp,
                 const unsigned short* __restrict__ Vp,
                 unsigned short* __restrict__ feats)
{
    constexpr int LDP = 72;  // 64 + 8 pad; row stride 144B (16B-aligned)
    __shared__ __align__(16) unsigned short Ks [64 * LDP];
    __shared__ __align__(16) unsigned short Vts[64 * LDP];  // transposed: [d][key]
    __shared__ __align__(16) unsigned short Ps [4][16 * LDP];

    const int tid = threadIdx.x;
    const int qb  = blockIdx.x;          // q-block of 64 rows
    const int bh  = blockIdx.y;
    const int b   = bh / H_, h = bh % H_;
    const int w   = tid >> 6, lane = tid & 63;
    const int lr  = lane & 15, lg = lane >> 4;

    // Q fragments for this wave's 16 rows (A-operand: m=lane&15, k=lg*8+j)
    const int qrow = qb * 64 + w * 16 + lr;
    const size_t qbase = ((size_t)(b * S_ + qrow)) * D_ + h * HD_;
    bf16x8 qf[2];
    qf[0] = *(const bf16x8*)(Qp + qbase + 0  + lg * 8);
    qf[1] = *(const bf16x8*)(Qp + qbase + 32 + lg * 8);

    float m_i[4], l_i[4];
    f32x4 o[4] = {};
    for (int r = 0; r < 4; ++r) { m_i[r] = -INFINITY; l_i[r] = 0.f; }

    for (int kb = 0; kb <= qb; ++kb) {
        __syncthreads();  // previous iter's LDS reads complete
        // ---- stage K (row-major) and V^T ----
        for (int t = 0; t < 2; ++t) {
            int idx = tid + t * 256;
            int row = idx >> 3, d0 = (idx & 7) * 8;
            size_t gbase = ((size_t)(b * S_ + kb * 64 + row)) * D_ + h * HD_ + d0;
            *(ushort8*)&Ks[row * LDP + d0] = *(const ushort8*)(Kp + gbase);
            ushort8 vv = *(const ushort8*)(Vp + gbase);
            for (int j = 0; j < 8; ++j) Vts[(d0 + j) * LDP + row] = vv[j];
        }
        __syncthreads();

        // ---- S = Q @ K^T  (B-operand: n=key=lane&15, k=d contiguous) ----
        f32x4 sf[4];
        for (int n = 0; n < 4; ++n) {
            f32x4 s = {0.f, 0.f, 0.f, 0.f};
            for (int ks = 0; ks < 2; ++ks) {
                bf16x8 kf = *(const bf16x8*)&Ks[(n * 16 + lr) * LDP + ks * 32 + lg * 8];
                s = __builtin_amdgcn_mfma_f32_16x16x32_bf16(qf[ks], kf, s, 0, 0, 0);
            }
            sf[n] = s;
        }
        // ---- scale + causal mask ----
        const int myq0 = qb * 64 + w * 16 + lg * 4;
        for (int n = 0; n < 4; ++n) {
            int key = kb * 64 + n * 16 + lr;
            for (int r = 0; r < 4; ++r) {
                float v = sf[n][r] * 0.125f;
                sf[n][r] = (key > myq0 + r) ? -INFINITY : v;
            }
        }
        // ---- online softmax (rows live in 16-lane groups) ----
        float alpha[4];
        for (int r = 0; r < 4; ++r) {
            float mx = fmaxf(fmaxf(sf[0][r], sf[1][r]), fmaxf(sf[2][r], sf[3][r]));
            for (int off = 1; off < 16; off <<= 1)
                mx = fmaxf(mx, __shfl_xor(mx, off, 64));
            float nm = fmaxf(m_i[r], mx);
            alpha[r] = __expf(m_i[r] - nm);
            m_i[r] = nm;
        }
        float rsum[4] = {0.f, 0.f, 0.f, 0.f};
        for (int n = 0; n < 4; ++n)
            for (int r = 0; r < 4; ++r) {
                float p = __expf(sf[n][r] - m_i[r]);
                sf[n][r] = p;
                rsum[r] += p;
            }
        for (int r = 0; r < 4; ++r) {
            float s = rsum[r];
            for (int off = 1; off < 16; off <<= 1)
                s += __shfl_xor(s, off, 64);
            l_i[r] = l_i[r] * alpha[r] + s;
            for (int n = 0; n < 4; ++n) o[n][r] *= alpha[r];
        }
        // ---- P: C-layout regs -> LDS (per-wave region) ----
        for (int n = 0; n < 4; ++n)
            for (int r = 0; r < 4; ++r)
                Ps[w][(lg * 4 + r) * LDP + n * 16 + lr] = f2b(sf[n][r]);
        __syncthreads();  // P visible (and K-reads done) before PV
        // ---- O += P @ V  (A=P from LDS in A-layout, B=V^T k-contiguous) ----
        for (int n = 0; n < 4; ++n) {
            for (int ks = 0; ks < 2; ++ks) {
                bf16x8 pf = *(const bf16x8*)&Ps[w][lr * LDP + ks * 32 + lg * 8];
                bf16x8 vf = *(const bf16x8*)&Vts[(n * 16 + lr) * LDP + ks * 32 + lg * 8];
                o[n] = __builtin_amdgcn_mfma_f32_16x16x32_bf16(pf, vf, o[n], 0, 0, 0);
            }
        }
    }

    // ---- epilogue: O/l -> feats (bf16), [B,S,D] head-concat layout ----
    const int q0 = qb * 64 + w * 16 + lg * 4;
    for (int r = 0; r < 4; ++r) {
        float inv = 1.0f / l_i[r];
        size_t base = ((size_t)(b * S_ + q0 + r)) * D_ + h * HD_;
        for (int n = 0; n < 4; ++n)
            feats[base + n * 16 + lr] = f2b(o[n][r] * inv);
    }
}

// ---------------------------------------------------------------------------
extern "C" void kernel_launch(void* const* d_in, const int* in_sizes, int n_in,
                              void* d_out, int out_size, void* d_ws, size_t ws_size,
                              hipStream_t stream) {
    const float* q  = (const float*)d_in[0];
    const float* k  = (const float*)d_in[1];
    const float* v  = (const float*)d_in[2];
    // d_in[3] = mask (causal, computed analytically; not read)
    const float* Wq = (const float*)d_in[4];
    const float* bq = (const float*)d_in[5];
    const float* Wk = (const float*)d_in[6];
    const float* bk = (const float*)d_in[7];
    const float* Wv = (const float*)d_in[8];
    const float* bv = (const float*)d_in[9];
    const float* Wo = (const float*)d_in[10];
    const float* bo = (const float*)d_in[11];
    float* out = (float*)d_out;

    const size_t npro = (size_t)B_ * S_ * D_;  // 6,291,456 elems
    unsigned short* Qp    = (unsigned short*)d_ws;         // bf16 bits
    unsigned short* Kp    = Qp + npro;
    unsigned short* Vp    = Kp + npro;
    unsigned short* feats = Vp + npro;                     // total ~50.3 MB

    const int M = B_ * S_;  // 8192
    dim3 blk(256);
    dim3 gP(M / 128, D_ / 128);  // (64, 6)

    gemm_bias<true,  false><<<gP, blk, 0, stream>>>(q, Wq, bq, Qp, M, D_, D_);
    gemm_bias<true,  false><<<gP, blk, 0, stream>>>(k, Wk, bk, Kp, M, D_, D_);
    gemm_bias<true,  false><<<gP, blk, 0, stream>>>(v, Wv, bv, Vp, M, D_, D_);

    attn_kernel<<<dim3(S_ / 64, B_ * H_), blk, 0, stream>>>(Qp, Kp, Vp, feats);

    gemm_bias<false, true ><<<gP, blk, 0, stream>>>(feats, Wo, bo, out, M, D_, D_);
}